// Round 6
// baseline (411.521 us; speedup 1.0000x reference)
//
#include <hip/hip_runtime.h>

namespace {

typedef float f32x4 __attribute__((ext_vector_type(4)));
typedef short bf16x8 __attribute__((ext_vector_type(8)));

constexpr float SM_SCALE = 0.08838834764831845f; // 1/sqrt(128)

#define MFMA16(a, b, c) __builtin_amdgcn_mfma_f32_16x16x32_bf16((a), (b), (c), 0, 0, 0)

__device__ __forceinline__ unsigned short bf16_rne(float x) {
  unsigned u = __float_as_uint(x);
  u += 0x7fffu + ((u >> 16) & 1u);
  return (unsigned short)(u >> 16);
}
__device__ __forceinline__ float bf16f(unsigned short h) {
  return __uint_as_float(((unsigned)h) << 16);
}
__device__ __forceinline__ void gld16(const void* g, void* l) {
  __builtin_amdgcn_global_load_lds(
      (const __attribute__((address_space(1))) unsigned int*)g,
      (__attribute__((address_space(3))) unsigned int*)l, 16, 0, 0);
}
__device__ __forceinline__ uint4 pack8(const unsigned short* h) {
  uint4 u;
  u.x = (unsigned)h[0] | ((unsigned)h[1] << 16);
  u.y = (unsigned)h[2] | ((unsigned)h[3] << 16);
  u.z = (unsigned)h[4] | ((unsigned)h[5] << 16);
  u.w = (unsigned)h[6] | ((unsigned)h[7] << 16);
  return u;
}

// ---------------------------------------------------------------------------
// prep_w: W[2048][128] fp32 -> Wt_hi/Wt_lo [3][128][2048] bf16 (transposed).
// ---------------------------------------------------------------------------
__global__ void prep_w(const float* __restrict__ Wq, const float* __restrict__ Wk,
                       const float* __restrict__ Wv,
                       unsigned short* __restrict__ WtH, unsigned short* __restrict__ WtL) {
  const int tg = blockIdx.x * 256 + threadIdx.x;   // 0..98303
  const int mi = tg >> 15;                          // 0=q 1=k 2=v
  const int rem = tg & 32767;
  const int n = rem & 127;
  const int k0 = (rem >> 7) * 8;
  const float* W = (mi == 0) ? Wq : ((mi == 1) ? Wk : Wv);
  unsigned short hv[8], lv[8];
#pragma unroll
  for (int e = 0; e < 8; ++e) {
    float xx = W[(size_t)(k0 + e) * 128 + n];
    unsigned short hh = bf16_rne(xx);
    hv[e] = hh;
    lv[e] = bf16_rne(xx - bf16f(hh));
  }
  const size_t off = (size_t)mi * 262144 + (size_t)n * 2048 + k0;
  *(uint4*)(WtH + off) = pack8(hv);
  *(uint4*)(WtL + off) = pack8(lv);
}

// ---------------------------------------------------------------------------
// qkv_gemm v4: 2-phase pipelined split-bf16 MFMA. BM=64 BN=128 BK=64.
// Grid 768 (1D, XCD-chunked so the 3 matrices of one m-tile share an XCD).
// B double-buffered via global_load_lds issued AFTER the second barrier ->
// drained one full compute phase later (latency hidden).
// ---------------------------------------------------------------------------
__global__ __launch_bounds__(256, 2) void qkv_gemm(
    const float* __restrict__ x,
    const unsigned short* __restrict__ WtH, const unsigned short* __restrict__ WtL,
    const float* __restrict__ bq, const float* __restrict__ bk, const float* __restrict__ bv,
    unsigned short* __restrict__ qh, unsigned short* __restrict__ ql,
    unsigned short* __restrict__ kh, unsigned short* __restrict__ kl,
    unsigned short* __restrict__ vTh, unsigned short* __restrict__ vTl) {
  __shared__ __align__(16) unsigned short sm[40960];   // 80 KB
  unsigned short* AsH = sm;            // [64][64] swizzled
  unsigned short* AsL = sm + 4096;
  // B buffers: BsH(buf) = sm + 8192 + buf*16384, BsL = BsH + 8192  ([128][64])

  const int bid = blockIdx.x;
  const int L = 96 * (bid & 7) + (bid >> 3);   // XCD-chunk: 768 = 8 x 96
  const int mi = L % 3;
  const int m0 = (L / 3) * 64;
  const int t = threadIdx.x;
  const int w = t >> 6, l = t & 63, g = l >> 4, lm = l & 15;
  const int wr = w >> 1, wc = w & 1;
  const int sw = (lm & 7) << 3;
  const unsigned short* WhP = WtH + (size_t)mi * 262144;
  const unsigned short* WlP = WtL + (size_t)mi * 262144;
  const float* bias = (mi == 0) ? bq : ((mi == 1) ? bk : bv);

  const int arow = t >> 4, ac4 = (t & 15) * 4;   // A map (4 iters of +16 rows)
  const int brow_l = l >> 3, bk8 = (l & 7) * 8;  // B map within 1KB block

  const f32x4 zf = {0.f, 0.f, 0.f, 0.f};
  f32x4 acc[2][4];
#pragma unroll
  for (int m = 0; m < 2; ++m)
#pragma unroll
    for (int n = 0; n < 4; ++n) acc[m][n] = zf;

  float4 av[4];
  // prologue: stage B buf0 + A regs for kc=0
#pragma unroll
  for (int i = 0; i < 4; ++i) {
    const int j = w * 4 + i;
    const int n = j * 8 + brow_l;
    const size_t go = (size_t)n * 2048 + 0 + (bk8 ^ ((n & 7) << 3));
    gld16(WhP + go, sm + 8192 + j * 512);
    gld16(WlP + go, sm + 16384 + j * 512);
  }
#pragma unroll
  for (int i = 0; i < 4; ++i)
    av[i] = *(const float4*)(x + (size_t)(m0 + arow + 16 * i) * 2048 + ac4);

  int cur = 0;
  for (int kc = 0; kc < 2048; kc += 64) {
    __syncthreads();   // drains B[cur] DMA + av loads (issued one compute ago)
    // A: convert regs -> hi/lo, swizzled LDS
#pragma unroll
    for (int i = 0; i < 4; ++i) {
      const int row = arow + 16 * i;
      const int idx = row * 64 + (ac4 ^ ((row & 7) << 3));
      ushort4 hh, ll;
      hh.x = bf16_rne(av[i].x); ll.x = bf16_rne(av[i].x - bf16f(hh.x));
      hh.y = bf16_rne(av[i].y); ll.y = bf16_rne(av[i].y - bf16f(hh.y));
      hh.z = bf16_rne(av[i].z); ll.z = bf16_rne(av[i].z - bf16f(hh.z));
      hh.w = bf16_rne(av[i].w); ll.w = bf16_rne(av[i].w - bf16f(hh.w));
      *(ushort4*)&AsH[idx] = hh;
      *(ushort4*)&AsL[idx] = ll;
    }
    __syncthreads();   // As visible (B[cur] already drained at barrier 1)

    // issue NEXT tile's loads now -> drained only at next iteration's barrier 1
    if (kc + 64 < 2048) {
#pragma unroll
      for (int i = 0; i < 4; ++i) {
        const int j = w * 4 + i;
        const int n = j * 8 + brow_l;
        const size_t go = (size_t)n * 2048 + (kc + 64) + (bk8 ^ ((n & 7) << 3));
        gld16(WhP + go, sm + 8192 + (cur ^ 1) * 16384 + j * 512);
        gld16(WlP + go, sm + 8192 + (cur ^ 1) * 16384 + 8192 + j * 512);
      }
#pragma unroll
      for (int i = 0; i < 4; ++i)
        av[i] = *(const float4*)(x + (size_t)(m0 + arow + 16 * i) * 2048 + kc + 64 + ac4);
    }

    const unsigned short* BH = sm + 8192 + cur * 16384;
    const unsigned short* BL = BH + 8192;
    __builtin_amdgcn_s_setprio(1);
#pragma unroll
    for (int ks = 0; ks < 2; ++ks) {
      const int kb = ks * 32 + g * 8;
      bf16x8 ah[2], al_[2], bh_[4], bl_[4];
#pragma unroll
      for (int m = 0; m < 2; ++m) {
        const int row = wr * 32 + m * 16 + lm;
        const int idx = row * 64 + (kb ^ sw);
        ah[m] = *(const bf16x8*)&AsH[idx];
        al_[m] = *(const bf16x8*)&AsL[idx];
      }
#pragma unroll
      for (int n = 0; n < 4; ++n) {
        const int row = wc * 64 + n * 16 + lm;
        const int idx = row * 64 + (kb ^ sw);
        bh_[n] = *(const bf16x8*)&BH[idx];
        bl_[n] = *(const bf16x8*)&BL[idx];
      }
#pragma unroll
      for (int m = 0; m < 2; ++m)
#pragma unroll
        for (int n = 0; n < 4; ++n) {
          acc[m][n] = MFMA16(ah[m], bh_[n], acc[m][n]);
          acc[m][n] = MFMA16(ah[m], bl_[n], acc[m][n]);
          acc[m][n] = MFMA16(al_[m], bh_[n], acc[m][n]);
        }
    }
    __builtin_amdgcn_s_setprio(0);
    cur ^= 1;
  }

  // ---- epilogue: C -> LDS fp32, then coalesced 16B stores ----
  __syncthreads();
  float* Cb = (float*)sm;   // [64][128] = 32 KB
#pragma unroll
  for (int n = 0; n < 4; ++n) {
    const int col = wc * 64 + n * 16 + lm;
    const float bn = bias[col];
#pragma unroll
    for (int m = 0; m < 2; ++m)
#pragma unroll
      for (int r = 0; r < 4; ++r)
        Cb[(wr * 32 + m * 16 + g * 4 + r) * 128 + col] = acc[m][n][r] + bn;
  }
  __syncthreads();

  if (mi < 2) {
    unsigned short* oh = (mi == 0) ? qh : kh;
    unsigned short* ol = (mi == 0) ? ql : kl;
    const int c8 = (t & 15) * 8;
#pragma unroll
    for (int i = 0; i < 4; ++i) {
      const int row = i * 16 + (t >> 4);
      float v8[8];
      *(float4*)(v8)     = *(const float4*)&Cb[row * 128 + c8];
      *(float4*)(v8 + 4) = *(const float4*)&Cb[row * 128 + c8 + 4];
      unsigned short h8[8], l8[8];
#pragma unroll
      for (int j = 0; j < 8; ++j) {
        h8[j] = bf16_rne(v8[j]);
        l8[j] = bf16_rne(v8[j] - bf16f(h8[j]));
      }
      const size_t o = (size_t)(m0 + row) * 128 + c8;
      *(uint4*)(oh + o) = pack8(h8);
      *(uint4*)(ol + o) = pack8(l8);
    }
  } else {
    const int bidx = m0 >> 12, tb0 = m0 & 4095;
    const int tc8 = (t & 7) * 8;
#pragma unroll
    for (int i = 0; i < 4; ++i) {
      const int h = i * 32 + (t >> 3);
      float v8[8];
#pragma unroll
      for (int j = 0; j < 8; ++j) v8[j] = Cb[(tc8 + j) * 128 + h];
      unsigned short h8[8], l8[8];
#pragma unroll
      for (int j = 0; j < 8; ++j) {
        h8[j] = bf16_rne(v8[j]);
        l8[j] = bf16_rne(v8[j] - bf16f(h8[j]));
      }
      const size_t o = ((size_t)bidx * 128 + h) * 4096 + tb0 + tc8;
      *(uint4*)(vTh + o) = pack8(h8);
      *(uint4*)(vTl + o) = pack8(l8);
    }
  }
}

// ---------------------------------------------------------------------------
// attn v2: BQ=128 (4 waves x 32 q-rows, 2 q-subtiles), BK=64, kv-split-4.
// One qb per block, heavy-qb dispatched first. 512 blocks, 80 KB LDS, 2/CU.
// 192 MFMA/wave per tile (2x round-5 density per barrier pair).
// ---------------------------------------------------------------------------
__global__ __launch_bounds__(256, 2) void attn(
    const unsigned short* __restrict__ qh, const unsigned short* __restrict__ ql,
    const unsigned short* __restrict__ kh, const unsigned short* __restrict__ kl,
    const unsigned short* __restrict__ vTh, const unsigned short* __restrict__ vTl,
    float* __restrict__ OP, float* __restrict__ ML) {
  __shared__ __align__(16) unsigned short sm[40960];  // 80 KB
  unsigned short* KhL = sm;            // [64][128] swz
  unsigned short* KlL = sm + 8192;
  unsigned short* VhL = sm + 16384;    // [128][64] swz (h-major)
  unsigned short* VlL = sm + 24576;
  unsigned short* PhL = sm + 32768;    // [4 waves][16][64] swz (reused per q-half)
  unsigned short* PlL = sm + 36864;

  const int b = blockIdx.y, bx = blockIdx.x;
  const int qb = 31 - (bx >> 2);       // heavy first
  const int s = bx & 3;
  const int q0 = qb * 128;
  const int part = b * 128 + qb * 4 + s;
  const int t = threadIdx.x, w = t >> 6, l = t & 63, g = l >> 4, lm = l & 15;
  const int sw8 = (lm & 7) << 3;
  const size_t bT = (size_t)b * 4096;
  const f32x4 zf = {0.f, 0.f, 0.f, 0.f};

  const int krow_l = l >> 4;   // K: block j covers kv rows 4j..4j+3
  const int kh8 = (l & 15) * 8;
  const int vrow_l = l >> 3;   // V: block j covers h rows 8j..8j+7
  const int vk8 = (l & 7) * 8;

  // Q fragments: wave w owns q rows q0 + w*32 + qt*16 + lm
  bf16x8 qfh[2][4], qfl[2][4];
#pragma unroll
  for (int qt = 0; qt < 2; ++qt) {
    const size_t qoff = (bT + q0 + w * 32 + qt * 16 + lm) * 128;
#pragma unroll
    for (int ks = 0; ks < 4; ++ks) {
      qfh[qt][ks] = *(const bf16x8*)(qh + qoff + ks * 32 + g * 8);
      qfl[qt][ks] = *(const bf16x8*)(ql + qoff + ks * 32 + g * 8);
    }
  }

  f32x4 o[2][8];
#pragma unroll
  for (int qt = 0; qt < 2; ++qt)
#pragma unroll
    for (int n = 0; n < 8; ++n) o[qt][n] = zf;
  float mrow[2] = {-1e30f, -1e30f}, lrow[2] = {0.f, 0.f};
  const int nt = 2 * qb + 2;
  const int wb = w * 1024;

  for (int ti = s; ti < nt; ti += 4) {
    const int t0 = ti * 64;
    __syncthreads();   // previous tile compute done with LDS
#pragma unroll
    for (int i = 0; i < 4; ++i) {
      const int j = w * 4 + i;
      const int krow = 4 * j + krow_l;
      const size_t kgo = (bT + t0 + krow) * 128 + (kh8 ^ ((krow & 7) << 3));
      gld16(kh + kgo, KhL + j * 512);
      gld16(kl + kgo, KlL + j * 512);
      const int hrow = 8 * j + vrow_l;
      const size_t vgo = ((size_t)b * 128 + hrow) * 4096 + t0 + (vk8 ^ ((hrow & 7) << 3));
      gld16(vTh + vgo, VhL + j * 512);
      gld16(vTl + vgo, VlL + j * 512);
    }
    __syncthreads();   // DMA drained, K/V staged

    // ---- S^T = K * Q^T (split 3-pass): [64 kv][32 q] per wave ----
    f32x4 sa[4][2];
#pragma unroll
    for (int m = 0; m < 4; ++m) { sa[m][0] = zf; sa[m][1] = zf; }
    __builtin_amdgcn_s_setprio(1);
#pragma unroll
    for (int ks = 0; ks < 4; ++ks) {
      const int kb = (ks * 32 + g * 8) ^ sw8;
#pragma unroll
      for (int m = 0; m < 4; ++m) {
        const bf16x8 kf = *(const bf16x8*)&KhL[(m * 16 + lm) * 128 + kb];
        const bf16x8 lf = *(const bf16x8*)&KlL[(m * 16 + lm) * 128 + kb];
        sa[m][0] = MFMA16(kf, qfh[0][ks], sa[m][0]);
        sa[m][0] = MFMA16(kf, qfl[0][ks], sa[m][0]);
        sa[m][0] = MFMA16(lf, qfh[0][ks], sa[m][0]);
        sa[m][1] = MFMA16(kf, qfh[1][ks], sa[m][1]);
        sa[m][1] = MFMA16(kf, qfl[1][ks], sa[m][1]);
        sa[m][1] = MFMA16(lf, qfh[1][ks], sa[m][1]);
      }
    }
    __builtin_amdgcn_s_setprio(0);

    // ---- per q-half: softmax + P + PV ----
#pragma unroll
    for (int qt = 0; qt < 2; ++qt) {
      const int qg = q0 + w * 32 + qt * 16 + lm;
      float pv_[16];
      float mt = -1e30f;
#pragma unroll
      for (int m = 0; m < 4; ++m)
#pragma unroll
        for (int r = 0; r < 4; ++r) {
          const int kvg = t0 + m * 16 + g * 4 + r;
          const float sv = (kvg <= qg) ? sa[m][qt][r] * SM_SCALE : -1e30f;
          pv_[m * 4 + r] = sv;
          mt = fmaxf(mt, sv);
        }
      mt = fmaxf(mt, __shfl_xor(mt, 16));
      mt = fmaxf(mt, __shfl_xor(mt, 32));
      const float mnew = fmaxf(mrow[qt], mt);
      const float sc = __expf(mrow[qt] - mnew);
      float lsum = 0.f;
#pragma unroll
      for (int j = 0; j < 16; ++j) {
        const float pe = (pv_[j] > -9e29f) ? __expf(pv_[j] - mnew) : 0.f;
        pv_[j] = pe;
        lsum += pe;
      }
      lsum += __shfl_xor(lsum, 16);
      lsum += __shfl_xor(lsum, 32);
      lrow[qt] = lrow[qt] * sc + lsum;
      mrow[qt] = mnew;
      float scr[4];
#pragma unroll
      for (int r = 0; r < 4; ++r) scr[r] = __shfl(sc, g * 4 + r);
#pragma unroll
      for (int n = 0; n < 8; ++n)
#pragma unroll
        for (int r = 0; r < 4; ++r) o[qt][n][r] *= scr[r];

      // P split hi/lo -> per-wave swizzled LDS (same-wave ordering, no barrier)
#pragma unroll
      for (int m = 0; m < 4; ++m)
#pragma unroll
        for (int j2 = 0; j2 < 2; ++j2) {
          const int kv0 = m * 16 + g * 4 + j2 * 2;
          const float p0f = pv_[m * 4 + j2 * 2];
          const float p1f = pv_[m * 4 + j2 * 2 + 1];
          ushort2 h2, l2;
          h2.x = bf16_rne(p0f); l2.x = bf16_rne(p0f - bf16f(h2.x));
          h2.y = bf16_rne(p1f); l2.y = bf16_rne(p1f - bf16f(h2.y));
          *(ushort2*)&PhL[wb + lm * 64 + (kv0 ^ sw8)] = h2;
          *(ushort2*)&PlL[wb + lm * 64 + (kv0 ^ sw8)] = l2;
        }
      const bf16x8 pAh0 = *(const bf16x8*)&PhL[wb + lm * 64 + ((g * 8) ^ sw8)];
      const bf16x8 pAl0 = *(const bf16x8*)&PlL[wb + lm * 64 + ((g * 8) ^ sw8)];
      const bf16x8 pAh1 = *(const bf16x8*)&PhL[wb + lm * 64 + ((32 + g * 8) ^ sw8)];
      const bf16x8 pAl1 = *(const bf16x8*)&PlL[wb + lm * 64 + ((32 + g * 8) ^ sw8)];

      __builtin_amdgcn_s_setprio(1);
#pragma unroll
      for (int n = 0; n < 8; ++n) {
        const int vb = (n * 16 + lm) * 64;
        const bf16x8 vh0 = *(const bf16x8*)&VhL[vb + ((g * 8) ^ sw8)];
        const bf16x8 vl0 = *(const bf16x8*)&VlL[vb + ((g * 8) ^ sw8)];
        o[qt][n] = MFMA16(pAh0, vh0, o[qt][n]);
        o[qt][n] = MFMA16(pAh0, vl0, o[qt][n]);
        o[qt][n] = MFMA16(pAl0, vh0, o[qt][n]);
        const bf16x8 vh1 = *(const bf16x8*)&VhL[vb + ((32 + g * 8) ^ sw8)];
        const bf16x8 vl1 = *(const bf16x8*)&VlL[vb + ((32 + g * 8) ^ sw8)];
        o[qt][n] = MFMA16(pAh1, vh1, o[qt][n]);
        o[qt][n] = MFMA16(pAh1, vl1, o[qt][n]);
        o[qt][n] = MFMA16(pAl1, vh1, o[qt][n]);
      }
      __builtin_amdgcn_s_setprio(0);
    } // qt
  } // kv tiles

  // ---- store partials (128 rows/part) ----
  float* OPp = OP + (size_t)part * 16384;
#pragma unroll
  for (int qt = 0; qt < 2; ++qt)
#pragma unroll
    for (int n = 0; n < 8; ++n)
#pragma unroll
      for (int r = 0; r < 4; ++r)
        OPp[(size_t)(w * 32 + qt * 16 + g * 4 + r) * 128 + n * 16 + lm] = o[qt][n][r];
  if (l < 16) {
#pragma unroll
    for (int qt = 0; qt < 2; ++qt) {
      ML[((size_t)part * 128 + w * 32 + qt * 16 + l) * 2 + 0] = mrow[qt];
      ML[((size_t)part * 128 + w * 32 + qt * 16 + l) * 2 + 1] = lrow[qt];
    }
  }
}

// ---------------------------------------------------------------------------
// combine: merge the 4 kv-split partials per q-row. 256 blocks x 256 thr.
// ---------------------------------------------------------------------------
__global__ void combine(const float* __restrict__ OP, const float* __restrict__ ML,
                        float* __restrict__ out) {
  const int xg = blockIdx.x;
  const int b = xg >> 6;
  const int t = threadIdx.x;
  const int r = t >> 2, hq = (t & 3) * 32;
  const int rowb = (xg & 63) * 64 + r;     // row within batch
  const int qb = rowb >> 7, rl = rowb & 127;
  const int p0 = b * 128 + qb * 4;
  float m[4], ll[4];
#pragma unroll
  for (int s2 = 0; s2 < 4; ++s2) {
    m[s2]  = ML[((size_t)(p0 + s2) * 128 + rl) * 2 + 0];
    ll[s2] = ML[((size_t)(p0 + s2) * 128 + rl) * 2 + 1];
  }
  const float mx = fmaxf(fmaxf(m[0], m[1]), fmaxf(m[2], m[3]));
  float wgt[4], den = 0.f;
#pragma unroll
  for (int s2 = 0; s2 < 4; ++s2) {
    wgt[s2] = __expf(m[s2] - mx);
    den += wgt[s2] * ll[s2];
  }
  const float inv = 1.f / den;
  float* op = out + ((size_t)(b * 4096 + rowb)) * 128 + hq;
#pragma unroll
  for (int j = 0; j < 8; ++j) {
    float ax = 0.f, ay = 0.f, az = 0.f, aw = 0.f;
#pragma unroll
    for (int s2 = 0; s2 < 4; ++s2) {
      const float4 pv = *(const float4*)(OP + ((size_t)(p0 + s2) * 16384 + rl * 128 + hq + j * 4));
      ax += wgt[s2] * pv.x; ay += wgt[s2] * pv.y;
      az += wgt[s2] * pv.z; aw += wgt[s2] * pv.w;
    }
    float4 ov; ov.x = ax * inv; ov.y = ay * inv; ov.z = az * inv; ov.w = aw * inv;
    *(float4*)(op + j * 4) = ov;
  }
}

}  // namespace

extern "C" void kernel_launch(void* const* d_in, const int* in_sizes, int n_in,
                              void* d_out, int out_size, void* d_ws, size_t ws_size,
                              hipStream_t stream) {
  // setup_inputs order: x, Wk, bk, Wq, bq, Wv, bv
  const float* x  = (const float*)d_in[0];
  const float* Wk = (const float*)d_in[1];
  const float* bk = (const float*)d_in[2];
  const float* Wq = (const float*)d_in[3];
  const float* bq = (const float*)d_in[4];
  const float* Wv = (const float*)d_in[5];
  const float* bv = (const float*)d_in[6];
  float* out = (float*)d_out;

  // workspace carve (~62 MB, same as round 5)
  unsigned short* WtH = (unsigned short*)d_ws;           // 3*128*2048
  unsigned short* WtL = WtH + 786432;
  unsigned short* qh  = WtL + 786432;                    // [16384][128] each
  unsigned short* ql  = qh + 2097152;
  unsigned short* kh  = ql + 2097152;
  unsigned short* kl  = kh + 2097152;
  unsigned short* vTh = kl + 2097152;                    // [4][128][4096]
  unsigned short* vTl = vTh + 2097152;
  float* OP = (float*)(vTl + 2097152);                   // [512][128][128]
  float* ML = OP + (size_t)512 * 16384;                  // [512][128][2]

  prep_w<<<384, 256, 0, stream>>>(Wq, Wk, Wv, WtH, WtL);
  qkv_gemm<<<768, 256, 0, stream>>>(x, WtH, WtL, bq, bk, bv,
                                    qh, ql, kh, kl, vTh, vTl);
  attn<<<dim3(128, 4), 256, 0, stream>>>(qh, ql, kh, kl, vTh, vTl, OP, ML);
  combine<<<256, 256, 0, stream>>>(OP, ML, out);
}